// Round 5
// baseline (1221.743 us; speedup 1.0000x reference)
//
#include <hip/hip_runtime.h>
#include <hip/hip_bf16.h>

// B=4, N=2048, DIMX=384, DIMQ=48, H=8.
// out_b = sum_h softmax(Q K^T/sqrt(48)) @ U_bh,  U_bh = X_b M_h^T,  M_h = W_rh W_vh.
// ws layout (bytes), with Xw/Wqw/Wkw aliased INSIDE Ow (dead until attn runs):
//   Mw  bf16 [h*384+c][k:384]          @ 0           (2,359,296)
//   Qw  bf16 [bh][i:2048][d:64 pad]    @ 2,359,296   (8,388,608)
//   Kw  bf16 same                      @ 10,747,904  (8,388,608)
//   UT  bf16 [bh][c:384][j:2048]       @ 19,136,512  (50,331,648)
//   Ow  bf16 [bh][i:2048][c:384]       @ 69,468,160  (50,331,648)
//     Xw  bf16 [b][j:2048][k:384]      @ 69,468,160  (6,291,456)   } alias Ow
//     Wqw bf16 [384][384]              @ 75,759,616  (294,912)     }
//     Wkw bf16 [384][384]              @ 76,054,528  (294,912)     }
// peak = 119,799,808 B

typedef short bf16x8 __attribute__((ext_vector_type(8)));
typedef float f32x4 __attribute__((ext_vector_type(4)));
typedef unsigned short ushort_t;
typedef unsigned int uint_t;

#define MFMA16(A, B, C) __builtin_amdgcn_mfma_f32_16x16x32_bf16(A, B, C, 0, 0, 0)

__device__ __forceinline__ ushort_t bits_bf16(float a) {
  __hip_bfloat16 h = __float2bfloat16(a);
  return *reinterpret_cast<ushort_t*>(&h);
}

// ---------- fp32 -> bf16 convert ----------
__global__ __launch_bounds__(256) void cvt_kernel(const float* __restrict__ src,
                                                  ushort_t* __restrict__ dst, int n4) {
  const int idx = blockIdx.x * 256 + threadIdx.x;
  if (idx >= n4) return;
  const float4 v = ((const float4*)src)[idx];
  ushort4 o;
  o.x = bits_bf16(v.x); o.y = bits_bf16(v.y); o.z = bits_bf16(v.z); o.w = bits_bf16(v.w);
  ((ushort4*)dst)[idx] = o;
}

// ---------- M_h = W_rh * W_vh  (fp32 compute, bf16 out; tiny) ----------
__global__ __launch_bounds__(256) void prep_m_kernel(const float* __restrict__ Wr,
                                                     const float* __restrict__ Wv,
                                                     ushort_t* __restrict__ Mw) {
  __shared__ float As[32][68];
  __shared__ float Bs[32][68];
  const int t = threadIdx.x;
  const int d0 = blockIdx.x << 6;
  const int k0 = blockIdx.y << 6;
  const int h  = blockIdx.z;
  const int ty = t >> 4, tx = t & 15;
  float acc[4][4] = {};
  for (int x0 = 0; x0 < 384; x0 += 32) {
#pragma unroll
    for (int rep = 0; rep < 2; ++rep) {
      int idx = t + (rep << 8);
      int row = idx >> 3, kq = (idx & 7) << 2;
      const float4 a = *(const float4*)&Wr[(size_t)(d0 + row) * 3072 + h * 384 + x0 + kq];
      As[kq + 0][row] = a.x; As[kq + 1][row] = a.y; As[kq + 2][row] = a.z; As[kq + 3][row] = a.w;
      int bro = idx >> 4, bc4 = (idx & 15) << 2;
      *(float4*)&Bs[bro][bc4] = *(const float4*)&Wv[(size_t)(h * 384 + x0 + bro) * 384 + k0 + bc4];
    }
    __syncthreads();
#pragma unroll
    for (int kk = 0; kk < 32; ++kk) {
      const float4 av = *(const float4*)&As[kk][ty << 2];
      const float4 bv = *(const float4*)&Bs[kk][tx << 2];
      const float a[4] = {av.x, av.y, av.z, av.w};
      const float b[4] = {bv.x, bv.y, bv.z, bv.w};
#pragma unroll
      for (int r = 0; r < 4; ++r)
#pragma unroll
        for (int c = 0; c < 4; ++c) acc[r][c] = fmaf(a[r], b[c], acc[r][c]);
    }
    __syncthreads();
  }
#pragma unroll
  for (int r = 0; r < 4; ++r)
#pragma unroll
    for (int c = 0; c < 4; ++c)
      Mw[(size_t)(h * 384 + d0 + (ty << 2) + r) * 384 + k0 + (tx << 2) + c] =
          bits_bf16(acc[r][c]);
}

// ---------- unified bf16 MFMA GEMM (unchanged) ----------
template <int MODE>
__global__ __launch_bounds__(256) void gemm_kernel(const ushort_t* __restrict__ Aall,
                                                   const ushort_t* __restrict__ Ball,
                                                   ushort_t* __restrict__ dst) {
  __shared__ ushort_t As[128 * 40];
  __shared__ ushort_t Bs[128 * 40];
  const int t = threadIdx.x;
  const int w = t >> 6, lane = t & 63, quad = lane >> 4, l16 = lane & 15;
  const int m0 = blockIdx.x << 7;
  const int n0 = blockIdx.y << 7;
  const ushort_t* Ap;
  const ushort_t* Bp;
  if (MODE == 0) {
    Ap = Aall; Bp = Ball;
  } else {
    const int bh = blockIdx.z, h = bh & 7, b = bh >> 3;
    Ap = Aall + (size_t)h * 384 * 384;
    Bp = Ball + (size_t)b * 2048 * 384;
  }
  const int wm = (w & 1) << 6, wn = (w >> 1) << 6;
  f32x4 acc[4][4] = {};

  for (int k0 = 0; k0 < 384; k0 += 32) {
    __syncthreads();
#pragma unroll
    for (int rep = 0; rep < 2; ++rep) {
      const int idx = t + (rep << 8);
      const int row = idx >> 2, c8 = (idx & 3) << 3;
      *(bf16x8*)&As[row * 40 + c8] = *(const bf16x8*)&Ap[(size_t)(m0 + row) * 384 + k0 + c8];
      *(bf16x8*)&Bs[row * 40 + c8] = *(const bf16x8*)&Bp[(size_t)(n0 + row) * 384 + k0 + c8];
    }
    __syncthreads();
    bf16x8 af[4], bfr[4];
#pragma unroll
    for (int x = 0; x < 4; ++x) {
      af[x] = *(const bf16x8*)&As[(wm + x * 16 + l16) * 40 + quad * 8];
      bfr[x] = *(const bf16x8*)&Bs[(wn + x * 16 + l16) * 40 + quad * 8];
    }
#pragma unroll
    for (int ti = 0; ti < 4; ++ti)
#pragma unroll
      for (int tj = 0; tj < 4; ++tj)
        acc[ti][tj] = MFMA16(af[ti], bfr[tj], acc[ti][tj]);
  }

#pragma unroll
  for (int ti = 0; ti < 4; ++ti) {
    const int gm0 = m0 + wm + ti * 16 + quad * 4;
#pragma unroll
    for (int tj = 0; tj < 4; ++tj) {
      const int gn = n0 + wn + tj * 16 + l16;
#pragma unroll
      for (int r = 0; r < 4; ++r) {
        const ushort_t v = bits_bf16(acc[ti][tj][r]);
        if (MODE == 0) {
          const int m = gm0 + r, b = m >> 11, i = m & 2047;
          const int h = gn / 48, dd = gn - h * 48;
          dst[(size_t)(((b << 3) + h) * 2048 + i) * 64 + dd] = v;
        } else {
          dst[((size_t)blockIdx.z * 384 + gm0 + r) * 2048 + gn] = v;
        }
      }
    }
  }
}

// ---------- fused attention, round-5: 256 queries/block (16 waves) ----------
// Rationale: U-stream traffic = N^2 * d / I_tile. Round-4 (I=64, 1024 blocks)
// moved 1.57 GB of U through L2/L3 (~8 TB/s observed = fabric-bound). I=256
// cuts unique U traffic to 0.39 GB. Per-wave working set identical to round 4
// (64i x 96c, ~220 regs); 16 waves = 4 i-subtiles x 4 roles; x4-duplicated U
// loads across i-subtiles hit per-CU L1/L2. 95 KB LDS -> 1 block/CU, 4 w/SIMD.
__global__ __launch_bounds__(1024) void attn_pv_kernel(const ushort_t* __restrict__ Qw,
                                                       const ushort_t* __restrict__ Kw,
                                                       const ushort_t* __restrict__ UT,
                                                       __hip_bfloat16* __restrict__ Ow) {
  __shared__ uint_t Ps[2][4][64 * 44];  // [buf][i_sub][row*44 + col]
  __shared__ float Lw[4][4][64];
  __shared__ float Ls[4][64];

  const int t = threadIdx.x;
  const int wid = t >> 6;           // 0..15
  const int isub = wid >> 2;        // i-subtile 0..3
  const int w = wid & 3;            // j-strip (scores) / c-quarter (PV)
  const int lane = t & 63, quad = lane >> 4, l16 = lane & 15;
  const int bid = blockIdx.x;       // 256 blocks: h|iblk|b
  const int h = bid & 7;
  const int i0 = (((bid >> 3) & 7) << 8) + (isub << 6);
  const int b = bid >> 6;
  const int bh = (b << 3) + h;

  const ushort_t* Qg = Qw + ((size_t)bh * 2048 + i0 + l16) * 64 + quad * 8;
  const ushort_t* Kg = Kw + ((size_t)bh * 2048 + w * 16 + l16) * 64 + quad * 8;
  const ushort_t* Ug = UT + ((size_t)bh * 384 + w * 96 + l16) * 2048 + quad * 8;

  bf16x8 qf[4][2];
#pragma unroll
  for (int ti = 0; ti < 4; ++ti)
#pragma unroll
    for (int kh = 0; kh < 2; ++kh)
      qf[ti][kh] = *(const bf16x8*)(Qg + (size_t)ti * 16 * 64 + kh * 32);

  f32x4 acc[4][6] = {};
  float lp[4] = {0.f, 0.f, 0.f, 0.f};
  // exp(s/sqrt(48)) = exp2(s * log2(e)/sqrt(48))
  const float c_exp = 0.14433756729740643f * 1.4426950408889634f;

  bf16x8 kf0 = *(const bf16x8*)(Kg);
  bf16x8 kf1 = *(const bf16x8*)(Kg + 32);
  int buf = 0;

  for (int jt = 0; jt < 32; ++jt) {
    const int j0 = jt << 6;
    // ---- issue U(jt) fragment loads first (waited at the barrier) ----
    bf16x8 uf[6][2];
#pragma unroll
    for (int tc = 0; tc < 6; ++tc) {
      const ushort_t* up = Ug + (size_t)tc * 16 * 2048 + j0;
      uf[tc][0] = *(const bf16x8*)(up);
      uf[tc][1] = *(const bf16x8*)(up + 32);
    }
    // ---- scores: S^T tile, (isub, j-strip w) ----
    f32x4 sv[4];
#pragma unroll
    for (int ti = 0; ti < 4; ++ti) {
      f32x4 z = {0.f, 0.f, 0.f, 0.f};
      z = MFMA16(kf0, qf[ti][0], z);
      z = MFMA16(kf1, qf[ti][1], z);
      sv[ti] = z;
    }
    // ---- prefetch next K tile ----
    const int jn = ((jt + 1) & 31) << 6;
    bf16x8 kn0 = *(const bf16x8*)(Kg + (size_t)jn * 64);
    bf16x8 kn1 = *(const bf16x8*)(Kg + (size_t)jn * 64 + 32);
    // ---- exp via exp2 + round-to-bf16 + v_perm pack ----
    uint_t pw[4][2];
#pragma unroll
    for (int ti = 0; ti < 4; ++ti) {
      const uint_t r0 = __float_as_uint(exp2f(sv[ti][0] * c_exp)) + 0x8000u;
      const uint_t r1 = __float_as_uint(exp2f(sv[ti][1] * c_exp)) + 0x8000u;
      const uint_t r2 = __float_as_uint(exp2f(sv[ti][2] * c_exp)) + 0x8000u;
      const uint_t r3 = __float_as_uint(exp2f(sv[ti][3] * c_exp)) + 0x8000u;
      const uint_t p0 = __builtin_amdgcn_perm(r1, r0, 0x07060302u);
      const uint_t p1 = __builtin_amdgcn_perm(r3, r2, 0x07060302u);
      pw[ti][0] = p0;
      pw[ti][1] = p1;
      lp[ti] += (__uint_as_float(p0 << 16) + __uint_as_float(p0 & 0xffff0000u)) +
                (__uint_as_float(p1 << 16) + __uint_as_float(p1 & 0xffff0000u));
    }
    // ---- write Ps[buf][isub] ----
    {
      uint_t* pb = &Ps[buf][isub][w * 8 + quad * 2];
#pragma unroll
      for (int ti = 0; ti < 4; ++ti)
        *(uint2*)(pb + (ti * 16 + l16) * 44) = uint2{pw[ti][0], pw[ti][1]};
    }
    __syncthreads();  // Ps ready + drains U/K loads issued at top
    // ---- P A-fragments ----
    bf16x8 pA[4][2];
#pragma unroll
    for (int ti = 0; ti < 4; ++ti)
#pragma unroll
      for (int ks = 0; ks < 2; ++ks)
        pA[ti][ks] = *(const bf16x8*)&Ps[buf][isub][(ti * 16 + l16) * 44 + ks * 16 + quad * 4];
    // ---- PV: all operands register-resident ----
#pragma unroll
    for (int tc = 0; tc < 6; ++tc) {
#pragma unroll
      for (int ti = 0; ti < 4; ++ti) acc[ti][tc] = MFMA16(pA[ti][0], uf[tc][0], acc[ti][tc]);
#pragma unroll
      for (int ti = 0; ti < 4; ++ti) acc[ti][tc] = MFMA16(pA[ti][1], uf[tc][1], acc[ti][tc]);
    }
    kf0 = kn0;
    kf1 = kn1;
    buf ^= 1;
  }

  // ---- softmax denominators (per i_sub, across its 4 waves) ----
#pragma unroll
  for (int ti = 0; ti < 4; ++ti) {
    lp[ti] += __shfl_xor(lp[ti], 16);
    lp[ti] += __shfl_xor(lp[ti], 32);
  }
  if (lane < 16) {
#pragma unroll
    for (int ti = 0; ti < 4; ++ti) Lw[isub][w][ti * 16 + lane] = lp[ti];
  }
  __syncthreads();
  if (t < 256) {
    const int is2 = t >> 6, r = t & 63;
    Ls[is2][r] = 1.0f / (Lw[is2][0][r] + Lw[is2][1][r] + Lw[is2][2][r] + Lw[is2][3][r]);
  }
  __syncthreads();

  // ---- epilogue: normalize, store bf16 partial O ----
  __hip_bfloat16* Op = Ow + ((size_t)bh * 2048 + i0) * 384 + w * 96 + l16;
#pragma unroll
  for (int ti = 0; ti < 4; ++ti)
#pragma unroll
    for (int r = 0; r < 4; ++r) {
      const float inv = Ls[isub][ti * 16 + quad * 4 + r];
      __hip_bfloat16* op = Op + (size_t)(ti * 16 + quad * 4 + r) * 384;
#pragma unroll
      for (int tc = 0; tc < 6; ++tc) op[tc * 16] = __float2bfloat16(acc[ti][tc][r] * inv);
    }
}

// ---------- reduce 8 heads ----------
__global__ __launch_bounds__(256) void reduce_kernel(const uint_t* __restrict__ OwU,
                                                     float2* __restrict__ out) {
  const int idx = blockIdx.x * 256 + threadIdx.x;
  const int b = idx / 393216;
  const int rem = idx - b * 393216;
  const uint_t* p = OwU + (size_t)b * 8 * 393216 + rem;
  float s0 = 0.f, s1 = 0.f;
#pragma unroll
  for (int h = 0; h < 8; ++h) {
    const uint_t v = p[(size_t)h * 393216];
    s0 += __uint_as_float(v << 16);
    s1 += __uint_as_float(v & 0xffff0000u);
  }
  out[(size_t)b * 393216 + rem] = float2{s0, s1};
}

extern "C" void kernel_launch(void* const* d_in, const int* in_sizes, int n_in,
                              void* d_out, int out_size, void* d_ws, size_t ws_size,
                              hipStream_t stream) {
  const float* X  = (const float*)d_in[0];
  const float* Wq = (const float*)d_in[1];
  const float* Wk = (const float*)d_in[2];
  const float* Wv = (const float*)d_in[3];
  const float* Wr = (const float*)d_in[4];

  char* ws = (char*)d_ws;
  ushort_t* Mw  = (ushort_t*)(ws);
  ushort_t* Qw  = (ushort_t*)(ws + 2359296);
  ushort_t* Kw  = (ushort_t*)(ws + 10747904);
  ushort_t* UT  = (ushort_t*)(ws + 19136512);
  __hip_bfloat16* Ow = (__hip_bfloat16*)(ws + 69468160);
  ushort_t* Xw  = (ushort_t*)(ws + 69468160);   // aliases Ow (dead until attn)
  ushort_t* Wqw = (ushort_t*)(ws + 75759616);   // aliases Ow
  ushort_t* Wkw = (ushort_t*)(ws + 76054528);   // aliases Ow

  hipMemsetAsync(ws + 2359296, 0, 16777216, stream);  // dq 48->64 pad of Q/K

  cvt_kernel<<<dim3(3072), 256, 0, stream>>>(X, Xw, 786432);
  cvt_kernel<<<dim3(144), 256, 0, stream>>>(Wq, Wqw, 36864);
  cvt_kernel<<<dim3(144), 256, 0, stream>>>(Wk, Wkw, 36864);
  prep_m_kernel<<<dim3(6, 6, 8), 256, 0, stream>>>(Wr, Wv, Mw);

  gemm_kernel<0><<<dim3(64, 3), 256, 0, stream>>>(Xw, Wqw, Qw);
  gemm_kernel<0><<<dim3(64, 3), 256, 0, stream>>>(Xw, Wkw, Kw);
  gemm_kernel<1><<<dim3(3, 16, 32), 256, 0, stream>>>(Mw, Xw, UT);

  attn_pv_kernel<<<dim3(256), 1024, 0, stream>>>(Qw, Kw, UT, Ow);
  reduce_kernel<<<dim3(6144), 256, 0, stream>>>((const uint_t*)Ow, (float2*)d_out);
}

// Round 6
// 482.181 us; speedup vs baseline: 2.5338x; 2.5338x over previous
//
#include <hip/hip_runtime.h>
#include <hip/hip_bf16.h>

// B=4, N=2048, DIMX=384, DIMQ=48, H=8.
// out_b = sum_h softmax(Q K^T/sqrt(48)) @ U_bh,  U_bh = X_b M_h^T,  M_h = W_rh W_vh.
// ws layout (bytes), with Xw/Wqw/Wkw aliased INSIDE Ow (dead until attn runs):
//   Mw  bf16 [h*384+c][k:384]          @ 0           (2,359,296)
//   Qw  bf16 [bh][i:2048][d:64 pad]    @ 2,359,296   (8,388,608)
//   Kw  bf16 same                      @ 10,747,904  (8,388,608)
//   UT  bf16 [bh][c:384][j:2048]       @ 19,136,512  (50,331,648)
//   Ow  bf16 [bh][i:2048][c:384]       @ 69,468,160  (50,331,648)
//     Xw  bf16 [b][j:2048][k:384]      @ 69,468,160  (6,291,456)   } alias Ow
//     Wqw bf16 [384][384]              @ 75,759,616  (294,912)     }
//     Wkw bf16 [384][384]              @ 76,054,528  (294,912)     }
// peak = 119,799,808 B

typedef short bf16x8 __attribute__((ext_vector_type(8)));
typedef float f32x4 __attribute__((ext_vector_type(4)));
typedef unsigned short ushort_t;
typedef unsigned int uint_t;

#define MFMA16(A, B, C) __builtin_amdgcn_mfma_f32_16x16x32_bf16(A, B, C, 0, 0, 0)

__device__ __forceinline__ ushort_t bits_bf16(float a) {
  __hip_bfloat16 h = __float2bfloat16(a);
  return *reinterpret_cast<ushort_t*>(&h);
}

// ---------- fp32 -> bf16 convert ----------
__global__ __launch_bounds__(256) void cvt_kernel(const float* __restrict__ src,
                                                  ushort_t* __restrict__ dst, int n4) {
  const int idx = blockIdx.x * 256 + threadIdx.x;
  if (idx >= n4) return;
  const float4 v = ((const float4*)src)[idx];
  ushort4 o;
  o.x = bits_bf16(v.x); o.y = bits_bf16(v.y); o.z = bits_bf16(v.z); o.w = bits_bf16(v.w);
  ((ushort4*)dst)[idx] = o;
}

// ---------- M_h = W_rh * W_vh  (fp32 compute, bf16 out; tiny) ----------
__global__ __launch_bounds__(256) void prep_m_kernel(const float* __restrict__ Wr,
                                                     const float* __restrict__ Wv,
                                                     ushort_t* __restrict__ Mw) {
  __shared__ float As[32][68];
  __shared__ float Bs[32][68];
  const int t = threadIdx.x;
  const int d0 = blockIdx.x << 6;
  const int k0 = blockIdx.y << 6;
  const int h  = blockIdx.z;
  const int ty = t >> 4, tx = t & 15;
  float acc[4][4] = {};
  for (int x0 = 0; x0 < 384; x0 += 32) {
#pragma unroll
    for (int rep = 0; rep < 2; ++rep) {
      int idx = t + (rep << 8);
      int row = idx >> 3, kq = (idx & 7) << 2;
      const float4 a = *(const float4*)&Wr[(size_t)(d0 + row) * 3072 + h * 384 + x0 + kq];
      As[kq + 0][row] = a.x; As[kq + 1][row] = a.y; As[kq + 2][row] = a.z; As[kq + 3][row] = a.w;
      int bro = idx >> 4, bc4 = (idx & 15) << 2;
      *(float4*)&Bs[bro][bc4] = *(const float4*)&Wv[(size_t)(h * 384 + x0 + bro) * 384 + k0 + bc4];
    }
    __syncthreads();
#pragma unroll
    for (int kk = 0; kk < 32; ++kk) {
      const float4 av = *(const float4*)&As[kk][ty << 2];
      const float4 bv = *(const float4*)&Bs[kk][tx << 2];
      const float a[4] = {av.x, av.y, av.z, av.w};
      const float b[4] = {bv.x, bv.y, bv.z, bv.w};
#pragma unroll
      for (int r = 0; r < 4; ++r)
#pragma unroll
        for (int c = 0; c < 4; ++c) acc[r][c] = fmaf(a[r], b[c], acc[r][c]);
    }
    __syncthreads();
  }
#pragma unroll
  for (int r = 0; r < 4; ++r)
#pragma unroll
    for (int c = 0; c < 4; ++c)
      Mw[(size_t)(h * 384 + d0 + (ty << 2) + r) * 384 + k0 + (tx << 2) + c] =
          bits_bf16(acc[r][c]);
}

// ---------- unified bf16 MFMA GEMM (unchanged) ----------
template <int MODE>
__global__ __launch_bounds__(256) void gemm_kernel(const ushort_t* __restrict__ Aall,
                                                   const ushort_t* __restrict__ Ball,
                                                   ushort_t* __restrict__ dst) {
  __shared__ ushort_t As[128 * 40];
  __shared__ ushort_t Bs[128 * 40];
  const int t = threadIdx.x;
  const int w = t >> 6, lane = t & 63, quad = lane >> 4, l16 = lane & 15;
  const int m0 = blockIdx.x << 7;
  const int n0 = blockIdx.y << 7;
  const ushort_t* Ap;
  const ushort_t* Bp;
  if (MODE == 0) {
    Ap = Aall; Bp = Ball;
  } else {
    const int bh = blockIdx.z, h = bh & 7, b = bh >> 3;
    Ap = Aall + (size_t)h * 384 * 384;
    Bp = Ball + (size_t)b * 2048 * 384;
  }
  const int wm = (w & 1) << 6, wn = (w >> 1) << 6;
  f32x4 acc[4][4] = {};

  for (int k0 = 0; k0 < 384; k0 += 32) {
    __syncthreads();
#pragma unroll
    for (int rep = 0; rep < 2; ++rep) {
      const int idx = t + (rep << 8);
      const int row = idx >> 2, c8 = (idx & 3) << 3;
      *(bf16x8*)&As[row * 40 + c8] = *(const bf16x8*)&Ap[(size_t)(m0 + row) * 384 + k0 + c8];
      *(bf16x8*)&Bs[row * 40 + c8] = *(const bf16x8*)&Bp[(size_t)(n0 + row) * 384 + k0 + c8];
    }
    __syncthreads();
    bf16x8 af[4], bfr[4];
#pragma unroll
    for (int x = 0; x < 4; ++x) {
      af[x] = *(const bf16x8*)&As[(wm + x * 16 + l16) * 40 + quad * 8];
      bfr[x] = *(const bf16x8*)&Bs[(wn + x * 16 + l16) * 40 + quad * 8];
    }
#pragma unroll
    for (int ti = 0; ti < 4; ++ti)
#pragma unroll
      for (int tj = 0; tj < 4; ++tj)
        acc[ti][tj] = MFMA16(af[ti], bfr[tj], acc[ti][tj]);
  }

#pragma unroll
  for (int ti = 0; ti < 4; ++ti) {
    const int gm0 = m0 + wm + ti * 16 + quad * 4;
#pragma unroll
    for (int tj = 0; tj < 4; ++tj) {
      const int gn = n0 + wn + tj * 16 + l16;
#pragma unroll
      for (int r = 0; r < 4; ++r) {
        const ushort_t v = bits_bf16(acc[ti][tj][r]);
        if (MODE == 0) {
          const int m = gm0 + r, b = m >> 11, i = m & 2047;
          const int h = gn / 48, dd = gn - h * 48;
          dst[(size_t)(((b << 3) + h) * 2048 + i) * 64 + dd] = v;
        } else {
          dst[((size_t)blockIdx.z * 384 + gm0 + r) * 2048 + gn] = v;
        }
      }
    }
  }
}

// ---------- fused attention, round-6: independent waves, barrier-free K-loop ----------
// Block = 4 INDEPENDENT waves = 4 i-subtiles (256 queries/block), c-quarter per block.
// Each wave: full 64-j scores (4 strips, C-layout), exp, wave-PRIVATE LDS round-trip
// to A-layout (no __syncthreads anywhere in the jt loop), PV over its 96 c-cols.
// Grid 1024 = [b:2b][cq:2b][iblk:3b][h:3b]; bid&7=h keeps one h per XCD and the
// 8 iblk-blocks sharing a (b,h,cq) U-stream land co-resident on one XCD (L2 window).
// Regs: qf32 + kf ring16 + uf ring16 + pA32 + misc ~ 150 VGPR + 96 AGPR acc < 256.
__global__ __launch_bounds__(256, 2) void attn_pv_kernel(const ushort_t* __restrict__ Qw,
                                                         const ushort_t* __restrict__ Kw,
                                                         const ushort_t* __restrict__ UT,
                                                         __hip_bfloat16* __restrict__ Ow) {
  __shared__ uint_t Ps[4][64 * 44];  // per-wave PRIVATE P: [i:64][j-pair:32], stride 44

  const int t = threadIdx.x;
  const int w = t >> 6, lane = t & 63, quad = lane >> 4, l16 = lane & 15;
  const int bid = blockIdx.x;
  const int h = bid & 7;
  const int iblk = (bid >> 3) & 7;
  const int cq = (bid >> 6) & 3;
  const int b = (bid >> 8) & 3;
  const int bh = (b << 3) + h;
  const int i0 = (iblk << 8) + (w << 6);   // this wave's 64 queries
  const int cbase = cq * 96;               // this block's 96 output cols

  const ushort_t* Qg = Qw + ((size_t)bh * 2048 + i0 + l16) * 64 + quad * 8;
  const ushort_t* Kg = Kw + ((size_t)bh * 2048 + l16) * 64 + quad * 8;
  const ushort_t* Ug = UT + ((size_t)(bh * 384 + cbase + l16)) * 2048 + quad * 8;
  uint_t* myPs = &Ps[w][0];

  // Q B-fragments, resident: B[k=d][n=i]
  bf16x8 qf[4][2];
#pragma unroll
  for (int ti = 0; ti < 4; ++ti)
#pragma unroll
    for (int kh = 0; kh < 2; ++kh)
      qf[ti][kh] = *(const bf16x8*)(Qg + (size_t)ti * 16 * 64 + kh * 32);

  f32x4 acc[4][6] = {};
  float lp[4] = {0.f, 0.f, 0.f, 0.f};
  // exp(s/sqrt(48)) = exp2(s * log2(e)/sqrt(48))
  const float c_exp = 0.14433756729740643f * 1.4426950408889634f;

  for (int jt = 0; jt < 32; ++jt) {
    const int j0 = jt << 6;
    // ---- U ring slots 0,1 issued early (covered by score phase) ----
    bf16x8 uf[2][2];
    {
      const ushort_t* u0 = Ug + (size_t)0 * 16 * 2048 + j0;
      const ushort_t* u1 = Ug + (size_t)1 * 16 * 2048 + j0;
      uf[0][0] = *(const bf16x8*)(u0); uf[0][1] = *(const bf16x8*)(u0 + 32);
      uf[1][0] = *(const bf16x8*)(u1); uf[1][1] = *(const bf16x8*)(u1 + 32);
    }
    // ---- scores, strip by strip (this wave owns ALL 64 j) ----
    bf16x8 kc0 = *(const bf16x8*)(Kg + (size_t)j0 * 64);
    bf16x8 kc1 = *(const bf16x8*)(Kg + (size_t)j0 * 64 + 32);
#pragma unroll
    for (int js = 0; js < 4; ++js) {
      bf16x8 kn0, kn1;
      if (js < 3) {
        const ushort_t* kp = Kg + (size_t)(j0 + (js + 1) * 16) * 64;
        kn0 = *(const bf16x8*)(kp);
        kn1 = *(const bf16x8*)(kp + 32);
      }
      f32x4 sv[4];
#pragma unroll
      for (int ti = 0; ti < 4; ++ti) {
        f32x4 z = {0.f, 0.f, 0.f, 0.f};
        z = MFMA16(kc0, qf[ti][0], z);
        z = MFMA16(kc1, qf[ti][1], z);
        sv[ti] = z;
      }
      // exp + round-to-bf16 + pack; write straight to private LDS
#pragma unroll
      for (int ti = 0; ti < 4; ++ti) {
        const uint_t r0 = __float_as_uint(exp2f(sv[ti][0] * c_exp)) + 0x8000u;
        const uint_t r1 = __float_as_uint(exp2f(sv[ti][1] * c_exp)) + 0x8000u;
        const uint_t r2 = __float_as_uint(exp2f(sv[ti][2] * c_exp)) + 0x8000u;
        const uint_t r3 = __float_as_uint(exp2f(sv[ti][3] * c_exp)) + 0x8000u;
        const uint_t p0 = __builtin_amdgcn_perm(r1, r0, 0x07060302u);
        const uint_t p1 = __builtin_amdgcn_perm(r3, r2, 0x07060302u);
        lp[ti] += (__uint_as_float(p0 << 16) + __uint_as_float(p0 & 0xffff0000u)) +
                  (__uint_as_float(p1 << 16) + __uint_as_float(p1 & 0xffff0000u));
        *(uint2*)(myPs + (ti * 16 + l16) * 44 + js * 8 + quad * 2) = uint2{p0, p1};
      }
      if (js < 3) { kc0 = kn0; kc1 = kn1; }
    }
    // ---- read back as A-fragments (same-wave dep: lgkmcnt only, NO barrier) ----
    bf16x8 pA[4][2];
#pragma unroll
    for (int ti = 0; ti < 4; ++ti)
#pragma unroll
      for (int ks = 0; ks < 2; ++ks)
        pA[ti][ks] = *(const bf16x8*)(myPs + (ti * 16 + l16) * 44 + ks * 16 + quad * 4);
    // ---- PV with 2-deep U ring ----
#pragma unroll
    for (int tc = 0; tc < 6; ++tc) {
      const int s = tc & 1;
#pragma unroll
      for (int ti = 0; ti < 4; ++ti) acc[ti][tc] = MFMA16(pA[ti][0], uf[s][0], acc[ti][tc]);
#pragma unroll
      for (int ti = 0; ti < 4; ++ti) acc[ti][tc] = MFMA16(pA[ti][1], uf[s][1], acc[ti][tc]);
      if (tc < 4) {
        const ushort_t* up = Ug + (size_t)(tc + 2) * 16 * 2048 + j0;
        uf[s][0] = *(const bf16x8*)(up);
        uf[s][1] = *(const bf16x8*)(up + 32);
      }
    }
  }

  // ---- softmax denominators: reduce over quads (within-wave), fetch via shfl ----
#pragma unroll
  for (int ti = 0; ti < 4; ++ti) {
    lp[ti] += __shfl_xor(lp[ti], 16);
    lp[ti] += __shfl_xor(lp[ti], 32);
  }
  // ---- epilogue: normalize, store bf16 partial O ----
  __hip_bfloat16* Op = Ow + ((size_t)bh * 2048 + i0) * 384 + cbase + l16;
#pragma unroll
  for (int ti = 0; ti < 4; ++ti)
#pragma unroll
    for (int r = 0; r < 4; ++r) {
      const float lsum = __shfl(lp[ti], quad * 4 + r);  // lane 4q+r holds row ti*16+4q+r
      const float inv = 1.0f / lsum;
      __hip_bfloat16* op = Op + (size_t)(ti * 16 + quad * 4 + r) * 384;
#pragma unroll
      for (int tc = 0; tc < 6; ++tc) op[tc * 16] = __float2bfloat16(acc[ti][tc][r] * inv);
    }
}

// ---------- reduce 8 heads ----------
__global__ __launch_bounds__(256) void reduce_kernel(const uint_t* __restrict__ OwU,
                                                     float2* __restrict__ out) {
  const int idx = blockIdx.x * 256 + threadIdx.x;
  const int b = idx / 393216;
  const int rem = idx - b * 393216;
  const uint_t* p = OwU + (size_t)b * 8 * 393216 + rem;
  float s0 = 0.f, s1 = 0.f;
#pragma unroll
  for (int h = 0; h < 8; ++h) {
    const uint_t v = p[(size_t)h * 393216];
    s0 += __uint_as_float(v << 16);
    s1 += __uint_as_float(v & 0xffff0000u);
  }
  out[(size_t)b * 393216 + rem] = float2{s0, s1};
}

extern "C" void kernel_launch(void* const* d_in, const int* in_sizes, int n_in,
                              void* d_out, int out_size, void* d_ws, size_t ws_size,
                              hipStream_t stream) {
  const float* X  = (const float*)d_in[0];
  const float* Wq = (const float*)d_in[1];
  const float* Wk = (const float*)d_in[2];
  const float* Wv = (const float*)d_in[3];
  const float* Wr = (const float*)d_in[4];

  char* ws = (char*)d_ws;
  ushort_t* Mw  = (ushort_t*)(ws);
  ushort_t* Qw  = (ushort_t*)(ws + 2359296);
  ushort_t* Kw  = (ushort_t*)(ws + 10747904);
  ushort_t* UT  = (ushort_t*)(ws + 19136512);
  __hip_bfloat16* Ow = (__hip_bfloat16*)(ws + 69468160);
  ushort_t* Xw  = (ushort_t*)(ws + 69468160);   // aliases Ow (dead until attn)
  ushort_t* Wqw = (ushort_t*)(ws + 75759616);   // aliases Ow
  ushort_t* Wkw = (ushort_t*)(ws + 76054528);   // aliases Ow

  hipMemsetAsync(ws + 2359296, 0, 16777216, stream);  // dq 48->64 pad of Q/K

  cvt_kernel<<<dim3(3072), 256, 0, stream>>>(X, Xw, 786432);
  cvt_kernel<<<dim3(144), 256, 0, stream>>>(Wq, Wqw, 36864);
  cvt_kernel<<<dim3(144), 256, 0, stream>>>(Wk, Wkw, 36864);
  prep_m_kernel<<<dim3(6, 6, 8), 256, 0, stream>>>(Wr, Wv, Mw);

  gemm_kernel<0><<<dim3(64, 3), 256, 0, stream>>>(Xw, Wqw, Qw);
  gemm_kernel<0><<<dim3(64, 3), 256, 0, stream>>>(Xw, Wkw, Kw);
  gemm_kernel<1><<<dim3(3, 16, 32), 256, 0, stream>>>(Mw, Xw, UT);

  attn_pv_kernel<<<dim3(1024), 256, 0, stream>>>(Qw, Kw, UT, Ow);
  reduce_kernel<<<dim3(6144), 256, 0, stream>>>((const uint_t*)Ow, (float2*)d_out);
}

// Round 7
// 406.846 us; speedup vs baseline: 3.0030x; 1.1852x over previous
//
#include <hip/hip_runtime.h>
#include <hip/hip_bf16.h>

// B=4, N=2048, DIMX=384, DIMQ=48, H=8.
// Restructure (round 7):  Z = softmax(QK^T/sqrt(48));  Y_bh = Z_bh X_b  (stream X^T,
// shared across h -> tiny L2 traffic);  out_b = sum_h Y_bh M_h^T  (one K=3072 GEMM,
// fp32 out, replaces U-GEMM + head-reduce).
// ws layout (bytes):
//   M2  bf16 [d:384][h*384+k : 3072]   @ 0           (2,359,296)
//   Qw  bf16 [bh][i:2048][d:64 pad]    @ 2,359,296   (8,388,608)
//   Kw  bf16 same                      @ 10,747,904  (8,388,608)
//   XT  bf16 [b][x:384][j:2048]        @ 19,136,512  (6,291,456)
//   Y   bf16 [b][i:2048][h*384+x:3072] @ 25,427,968  (50,331,648)
//   Xw  bf16 [b][j:2048][x:384]        @ 75,759,616  (6,291,456)
//   Wqw bf16 [384][384]                @ 82,051,072  (294,912)
//   Wkw bf16 [384][384]                @ 82,345,984  (294,912)
// total 82,640,896 B

typedef short bf16x8 __attribute__((ext_vector_type(8)));
typedef float f32x4 __attribute__((ext_vector_type(4)));
typedef unsigned short ushort_t;
typedef unsigned int uint_t;

#define MFMA16(A, B, C) __builtin_amdgcn_mfma_f32_16x16x32_bf16(A, B, C, 0, 0, 0)

__device__ __forceinline__ ushort_t bits_bf16(float a) {
  __hip_bfloat16 h = __float2bfloat16(a);
  return *reinterpret_cast<ushort_t*>(&h);
}

// ---------- fp32 -> bf16 convert ----------
__global__ __launch_bounds__(256) void cvt_kernel(const float* __restrict__ src,
                                                  ushort_t* __restrict__ dst, int n4) {
  const int idx = blockIdx.x * 256 + threadIdx.x;
  if (idx >= n4) return;
  const float4 v = ((const float4*)src)[idx];
  ushort4 o;
  o.x = bits_bf16(v.x); o.y = bits_bf16(v.y); o.z = bits_bf16(v.z); o.w = bits_bf16(v.w);
  ((ushort4*)dst)[idx] = o;
}

// ---------- fp32 X [b][j][x] -> bf16 XT [b][x][j] (LDS-tiled transpose) ----------
__global__ __launch_bounds__(256) void cvt_t_kernel(const float* __restrict__ X,
                                                    ushort_t* __restrict__ XT) {
  __shared__ float Ld[64][68];
  const int t = threadIdx.x;
  const int j0 = blockIdx.x << 6, x0 = blockIdx.y << 6, b = blockIdx.z;
  const float* Xp = X + (size_t)b * 2048 * 384;
#pragma unroll
  for (int rep = 0; rep < 4; ++rep) {
    const int idx = t + (rep << 8);
    const int jr = idx >> 4, x4 = (idx & 15) << 2;
    const float4 v = *(const float4*)&Xp[(size_t)(j0 + jr) * 384 + x0 + x4];
    Ld[jr][x4] = v.x; Ld[jr][x4 + 1] = v.y; Ld[jr][x4 + 2] = v.z; Ld[jr][x4 + 3] = v.w;
  }
  __syncthreads();
#pragma unroll
  for (int rep = 0; rep < 2; ++rep) {
    const int idx = t + (rep << 8);
    const int xr = idx >> 3, j8 = (idx & 7) << 3;
    ushort_t o[8];
#pragma unroll
    for (int e = 0; e < 8; ++e) o[e] = bits_bf16(Ld[j8 + e][xr]);
    ushort_t* dp = &XT[((size_t)b * 384 + x0 + xr) * 2048 + j0 + j8];
    *(ushort4*)dp = *(ushort4*)&o[0];
    *(ushort4*)(dp + 4) = *(ushort4*)&o[4];
  }
}

// ---------- M2[d][h*384+k] = sum_x Wr[d][h*384+x] * Wv[h*384+x][k] ----------
__global__ __launch_bounds__(256) void prep_m_kernel(const float* __restrict__ Wr,
                                                     const float* __restrict__ Wv,
                                                     ushort_t* __restrict__ M2) {
  __shared__ float As[32][68];
  __shared__ float Bs[32][68];
  const int t = threadIdx.x;
  const int d0 = blockIdx.x << 6;
  const int k0 = blockIdx.y << 6;
  const int h  = blockIdx.z;
  const int ty = t >> 4, tx = t & 15;
  float acc[4][4] = {};
  for (int x0 = 0; x0 < 384; x0 += 32) {
#pragma unroll
    for (int rep = 0; rep < 2; ++rep) {
      int idx = t + (rep << 8);
      int row = idx >> 3, kq = (idx & 7) << 2;
      const float4 a = *(const float4*)&Wr[(size_t)(d0 + row) * 3072 + h * 384 + x0 + kq];
      As[kq + 0][row] = a.x; As[kq + 1][row] = a.y; As[kq + 2][row] = a.z; As[kq + 3][row] = a.w;
      int bro = idx >> 4, bc4 = (idx & 15) << 2;
      *(float4*)&Bs[bro][bc4] = *(const float4*)&Wv[(size_t)(h * 384 + x0 + bro) * 384 + k0 + bc4];
    }
    __syncthreads();
#pragma unroll
    for (int kk = 0; kk < 32; ++kk) {
      const float4 av = *(const float4*)&As[kk][ty << 2];
      const float4 bv = *(const float4*)&Bs[kk][tx << 2];
      const float a[4] = {av.x, av.y, av.z, av.w};
      const float b[4] = {bv.x, bv.y, bv.z, bv.w};
#pragma unroll
      for (int r = 0; r < 4; ++r)
#pragma unroll
        for (int c = 0; c < 4; ++c) acc[r][c] = fmaf(a[r], b[c], acc[r][c]);
    }
    __syncthreads();
  }
#pragma unroll
  for (int r = 0; r < 4; ++r)
#pragma unroll
    for (int c = 0; c < 4; ++c)
      M2[(size_t)(d0 + (ty << 2) + r) * 3072 + h * 384 + k0 + (tx << 2) + c] =
          bits_bf16(acc[r][c]);
}

// ---------- bf16 MFMA GEMM, 128x128 tile ----------
// MODE 0 (Q/K proj): A=Xw[8192][384], B=W[384][384], K=384; store Qw-style bf16.
// MODE 2 (out):      A=Y_b[2048][3072] (z=b), B=M2[384][3072], K=3072; store fp32 out.
template <int MODE>
__global__ __launch_bounds__(256) void gemm_kernel(const ushort_t* __restrict__ Aall,
                                                   const ushort_t* __restrict__ Ball,
                                                   void* __restrict__ dstv) {
  constexpr int KD = (MODE == 0) ? 384 : 3072;
  __shared__ ushort_t As[128 * 40];
  __shared__ ushort_t Bs[128 * 40];
  const int t = threadIdx.x;
  const int w = t >> 6, lane = t & 63, quad = lane >> 4, l16 = lane & 15;
  const int m0 = blockIdx.x << 7;
  const int n0 = blockIdx.y << 7;
  const ushort_t* Ap = (MODE == 0) ? Aall : Aall + (size_t)blockIdx.z * 2048 * 3072;
  const ushort_t* Bp = Ball;
  const int wm = (w & 1) << 6, wn = (w >> 1) << 6;
  f32x4 acc[4][4] = {};

  for (int k0 = 0; k0 < KD; k0 += 32) {
    __syncthreads();
#pragma unroll
    for (int rep = 0; rep < 2; ++rep) {
      const int idx = t + (rep << 8);
      const int row = idx >> 2, c8 = (idx & 3) << 3;
      *(bf16x8*)&As[row * 40 + c8] = *(const bf16x8*)&Ap[(size_t)(m0 + row) * KD + k0 + c8];
      *(bf16x8*)&Bs[row * 40 + c8] = *(const bf16x8*)&Bp[(size_t)(n0 + row) * KD + k0 + c8];
    }
    __syncthreads();
    bf16x8 af[4], bfr[4];
#pragma unroll
    for (int x = 0; x < 4; ++x) {
      af[x] = *(const bf16x8*)&As[(wm + x * 16 + l16) * 40 + quad * 8];
      bfr[x] = *(const bf16x8*)&Bs[(wn + x * 16 + l16) * 40 + quad * 8];
    }
#pragma unroll
    for (int ti = 0; ti < 4; ++ti)
#pragma unroll
      for (int tj = 0; tj < 4; ++tj)
        acc[ti][tj] = MFMA16(af[ti], bfr[tj], acc[ti][tj]);
  }

#pragma unroll
  for (int ti = 0; ti < 4; ++ti) {
    const int gm0 = m0 + wm + ti * 16 + quad * 4;
#pragma unroll
    for (int tj = 0; tj < 4; ++tj) {
      const int gn = n0 + wn + tj * 16 + l16;
#pragma unroll
      for (int r = 0; r < 4; ++r) {
        if (MODE == 0) {
          const int m = gm0 + r, b = m >> 11, i = m & 2047;
          const int h = gn / 48, dd = gn - h * 48;
          ((ushort_t*)dstv)[(size_t)(((b << 3) + h) * 2048 + i) * 64 + dd] =
              bits_bf16(acc[ti][tj][r]);
        } else {
          ((float*)dstv)[(size_t)(blockIdx.z * 2048 + gm0 + r) * 384 + gn] = acc[ti][tj][r];
        }
      }
    }
  }
}

// ---------- fused attention (round-4 structure, X^T streamed) ----------
// Block: 64 queries x full 384 x-cols; 4 waves (j-strips for scores, x-quarters for PV).
// Single barrier/jt, double-buffered Ps (stride 44 words). B-operand = XT[b] — shared
// by all 8 heads; grid swizzle bid&7 -> (b, iblk lsb) so each XCD slot streams ONE X_b
// (48 KB/jt window, L2-resident across its ~64 co-scheduled blocks).
__global__ __launch_bounds__(256, 2) void attn_pv_kernel(const ushort_t* __restrict__ Qw,
                                                         const ushort_t* __restrict__ Kw,
                                                         const ushort_t* __restrict__ XT,
                                                         __hip_bfloat16* __restrict__ Yw) {
  __shared__ uint_t Ps[2][64 * 44];
  __shared__ float Lw[4][64];
  __shared__ float Ls[64];

  const int t = threadIdx.x;
  const int w = t >> 6, lane = t & 63, quad = lane >> 4, l16 = lane & 15;
  const int bid = blockIdx.x;  // bits: [0]=iblk_lsb [2:1]=b [6:3]=iblk_hi [9:7]=h
  const int ilsb = bid & 1;
  const int b = (bid >> 1) & 3;
  const int ihi = (bid >> 3) & 15;
  const int h = bid >> 7;
  const int iblk = (ihi << 1) | ilsb;
  const int i0 = iblk << 6;
  const int bh = (b << 3) + h;

  const ushort_t* Qg = Qw + ((size_t)bh * 2048 + i0 + l16) * 64 + quad * 8;
  const ushort_t* Kg = Kw + ((size_t)bh * 2048 + w * 16 + l16) * 64 + quad * 8;
  const ushort_t* Xg = XT + ((size_t)b * 384 + w * 96 + l16) * 2048 + quad * 8;

  bf16x8 qf[4][2];
#pragma unroll
  for (int ti = 0; ti < 4; ++ti)
#pragma unroll
    for (int kh = 0; kh < 2; ++kh)
      qf[ti][kh] = *(const bf16x8*)(Qg + (size_t)ti * 16 * 64 + kh * 32);

  f32x4 acc[4][6] = {};
  float lp[4] = {0.f, 0.f, 0.f, 0.f};
  // exp(s/sqrt(48)) = exp2(s * log2(e)/sqrt(48))
  const float c_exp = 0.14433756729740643f * 1.4426950408889634f;

  bf16x8 kf0 = *(const bf16x8*)(Kg);
  bf16x8 kf1 = *(const bf16x8*)(Kg + 32);
  int buf = 0;

  for (int jt = 0; jt < 32; ++jt) {
    const int j0 = jt << 6;
    // ---- issue X(jt) fragment loads first (waited at the barrier) ----
    bf16x8 uf[6][2];
#pragma unroll
    for (int tc = 0; tc < 6; ++tc) {
      const ushort_t* up = Xg + (size_t)tc * 16 * 2048 + j0;
      uf[tc][0] = *(const bf16x8*)(up);
      uf[tc][1] = *(const bf16x8*)(up + 32);
    }
    // ---- scores: S^T tile, wave w owns j-strip w*16..+15 ----
    f32x4 sv[4];
#pragma unroll
    for (int ti = 0; ti < 4; ++ti) {
      f32x4 z = {0.f, 0.f, 0.f, 0.f};
      z = MFMA16(kf0, qf[ti][0], z);
      z = MFMA16(kf1, qf[ti][1], z);
      sv[ti] = z;
    }
    // ---- prefetch next K tile ----
    const int jn = ((jt + 1) & 31) << 6;
    bf16x8 kn0 = *(const bf16x8*)(Kg + (size_t)jn * 64);
    bf16x8 kn1 = *(const bf16x8*)(Kg + (size_t)jn * 64 + 32);
    // ---- exp via exp2 + round-to-bf16 + v_perm pack; lp from f32 (cheap) ----
    uint_t pw[4][2];
#pragma unroll
    for (int ti = 0; ti < 4; ++ti) {
      const float e0 = exp2f(sv[ti][0] * c_exp);
      const float e1 = exp2f(sv[ti][1] * c_exp);
      const float e2 = exp2f(sv[ti][2] * c_exp);
      const float e3 = exp2f(sv[ti][3] * c_exp);
      lp[ti] += (e0 + e1) + (e2 + e3);
      const uint_t r0 = __float_as_uint(e0) + 0x8000u;
      const uint_t r1 = __float_as_uint(e1) + 0x8000u;
      const uint_t r2 = __float_as_uint(e2) + 0x8000u;
      const uint_t r3 = __float_as_uint(e3) + 0x8000u;
      pw[ti][0] = __builtin_amdgcn_perm(r1, r0, 0x07060302u);
      pw[ti][1] = __builtin_amdgcn_perm(r3, r2, 0x07060302u);
    }
    // ---- write Ps[buf] ----
    {
      uint_t* pb = &Ps[buf][w * 8 + quad * 2];
#pragma unroll
      for (int ti = 0; ti < 4; ++ti)
        *(uint2*)(pb + (ti * 16 + l16) * 44) = uint2{pw[ti][0], pw[ti][1]};
    }
    __syncthreads();  // Ps ready + drains X/K loads issued at top
    // ---- P A-fragments ----
    bf16x8 pA[4][2];
#pragma unroll
    for (int ti = 0; ti < 4; ++ti)
#pragma unroll
      for (int ks = 0; ks < 2; ++ks)
        pA[ti][ks] = *(const bf16x8*)&Ps[buf][(ti * 16 + l16) * 44 + ks * 16 + quad * 4];
    // ---- PV: all operands register-resident ----
#pragma unroll
    for (int tc = 0; tc < 6; ++tc) {
#pragma unroll
      for (int ti = 0; ti < 4; ++ti) acc[ti][tc] = MFMA16(pA[ti][0], uf[tc][0], acc[ti][tc]);
#pragma unroll
      for (int ti = 0; ti < 4; ++ti) acc[ti][tc] = MFMA16(pA[ti][1], uf[tc][1], acc[ti][tc]);
    }
    kf0 = kn0;
    kf1 = kn1;
    buf ^= 1;
  }

  // ---- softmax denominators ----
#pragma unroll
  for (int ti = 0; ti < 4; ++ti) {
    lp[ti] += __shfl_xor(lp[ti], 16);
    lp[ti] += __shfl_xor(lp[ti], 32);
  }
  if (lane < 16) {
#pragma unroll
    for (int ti = 0; ti < 4; ++ti) Lw[w][ti * 16 + lane] = lp[ti];
  }
  __syncthreads();
  if (t < 64) Ls[t] = 1.0f / (Lw[0][t] + Lw[1][t] + Lw[2][t] + Lw[3][t]);
  __syncthreads();

  // ---- epilogue: normalize, store bf16 Y[b][i][h*384 + x] ----
  __hip_bfloat16* Yp = Yw + (size_t)(b * 2048 + i0) * 3072 + h * 384 + w * 96 + l16;
#pragma unroll
  for (int ti = 0; ti < 4; ++ti)
#pragma unroll
    for (int r = 0; r < 4; ++r) {
      const float inv = Ls[ti * 16 + quad * 4 + r];
      __hip_bfloat16* op = Yp + (size_t)(ti * 16 + quad * 4 + r) * 3072;
#pragma unroll
      for (int tc = 0; tc < 6; ++tc) op[tc * 16] = __float2bfloat16(acc[ti][tc][r] * inv);
    }
}

extern "C" void kernel_launch(void* const* d_in, const int* in_sizes, int n_in,
                              void* d_out, int out_size, void* d_ws, size_t ws_size,
                              hipStream_t stream) {
  const float* X  = (const float*)d_in[0];
  const float* Wq = (const float*)d_in[1];
  const float* Wk = (const float*)d_in[2];
  const float* Wv = (const float*)d_in[3];
  const float* Wr = (const float*)d_in[4];

  char* ws = (char*)d_ws;
  ushort_t* M2  = (ushort_t*)(ws);
  ushort_t* Qw  = (ushort_t*)(ws + 2359296);
  ushort_t* Kw  = (ushort_t*)(ws + 10747904);
  ushort_t* XT  = (ushort_t*)(ws + 19136512);
  __hip_bfloat16* Yw = (__hip_bfloat16*)(ws + 25427968);
  ushort_t* Xw  = (ushort_t*)(ws + 75759616);
  ushort_t* Wqw = (ushort_t*)(ws + 82051072);
  ushort_t* Wkw = (ushort_t*)(ws + 82345984);

  hipMemsetAsync(ws + 2359296, 0, 16777216, stream);  // dq 48->64 pad of Q/K

  cvt_kernel<<<dim3(3072), 256, 0, stream>>>(X, Xw, 786432);
  cvt_t_kernel<<<dim3(32, 6, 4), 256, 0, stream>>>(X, XT);
  cvt_kernel<<<dim3(144), 256, 0, stream>>>(Wq, Wqw, 36864);
  cvt_kernel<<<dim3(144), 256, 0, stream>>>(Wk, Wkw, 36864);
  prep_m_kernel<<<dim3(6, 6, 8), 256, 0, stream>>>(Wr, Wv, M2);

  gemm_kernel<0><<<dim3(64, 3), 256, 0, stream>>>(Xw, Wqw, Qw);
  gemm_kernel<0><<<dim3(64, 3), 256, 0, stream>>>(Xw, Wkw, Kw);

  attn_pv_kernel<<<dim3(1024), 256, 0, stream>>>(Qw, Kw, XT, Yw);

  gemm_kernel<2><<<dim3(16, 3, 4), 256, 0, stream>>>((const ushort_t*)Yw, M2, d_out);
}